// Round 9
// baseline (36.471 us; speedup 1.0000x reference)
//
#include <hip/hip_runtime.h>
#include <hip/hip_bf16.h>
#include <cstdint>

// GraphLoss fused persistent-pipeline kernel.
// result = sum(w*gold) + logsumexp over all source->sink paths of (-path weight).
// lsexp_a(v[a]-W[a][b]) = s0 + log( sum_a exp(v[a]-s0) * exp(-W[a][b]) )
//
// R7/R8 post-mortem: the 63-level chain on one CU is latency-bound on the
// 1MB W stream (freshly written by prep on other XCDs' L2s -> ~1200cy dirty
// cross-XCD fetches; one CU sustains only ~70GB/s of that). Fix: make W
// *LDS-resident*. 5 chain workgroups each own a slice of levels
// {4,11,16,16,16}, convert w -> packed bf16 exp(-w) straight into their own
// 128KB LDS (coalesced float4 global reads), then run their bodies purely
// from LDS. z[64] hops wg->wg via agent-scope atomics + MAGIC flags.
// 128 gold wgs compute sum(w*gold) partials in parallel -> last chain wg.
// No inline-asm global loads anywhere => the whole R3-R6 vmcnt/register
// hazard class is structurally gone; __syncthreads is safe (no VMEM in
// flight during the chain).
//
// Flag protocol (graph-replay-safe): flags live in d_ws (poisoned 0xAA once,
// never re-poisoned). Producers set flag=MAGIC (release, agent scope) after
// data; consumers spin-acquire for MAGIC then reset flag to 0. Poison/0 both
// != MAGIC, and launches serialize on the stream => deterministic.
//
// Edge layout: e in [0,64): source->layer1 ; e = 64 + L*4096 + a*64 + b ;
// e = 258112 + j: layer64 -> sink.

typedef float f32x4 __attribute__((ext_vector_type(4)));
typedef float v2f   __attribute__((ext_vector_type(2)));
typedef unsigned int u32x4 __attribute__((ext_vector_type(4)));

#define NCH 5
#define NGOLD 128
#define TPB 256
#define MAXLV 16
#define SINK_BASE (64 + 63 * 4096)   // 258112
#define MAGIC 0x5EC0FFEEu

// ws layout: F = float view, U = uint view of d_ws
//   F[0..128)    gold partials
//   U[128..256)  gold flags
//   U[256..260)  chain handoff flags (producer wgid 0..3)
//   F[260..516)  zcom[4][64]

__global__ __launch_bounds__(TPB, 1)
void fused_kernel(const int* __restrict__ g, const float* __restrict__ w,
                  float* __restrict__ ws, float* __restrict__ out, int E) {
    __shared__ unsigned int wlds[MAXLV * 2048];   // 128KB packed bf16 W
    __shared__ __align__(16) float ubuf[2][64];
    __shared__ float zls[2];
    __shared__ float slds[64];
    __shared__ float gred[4];

    float* wsF = ws;
    unsigned int* wsU = (unsigned int*)ws;
    const int wgid = blockIdx.x;
    const int tid = threadIdx.x;
    const int wv = tid >> 6, l = tid & 63;

    if (wgid >= NCH) {
        // ---------------- gold reduction ----------------
        const int gw = wgid - NCH;
        const bool is64 = (g[1] == 0);   // graph int32 vs int64 words
        float s = 0.f;
        for (int e = gw * TPB + tid; e < E; e += NGOLD * TPB) {
            const int idx = 3 * e + 2;
            const int gv = is64 ? g[2 * idx] : g[idx];
            s += w[e] * (float)gv;
        }
        #pragma unroll
        for (int d = 1; d < 64; d <<= 1) s += __shfl_xor(s, d, 64);
        if (l == 0) gred[wv] = s;
        __syncthreads();
        if (tid == 0) {
            const float tt = gred[0] + gred[1] + gred[2] + gred[3];
            __hip_atomic_store(&wsF[gw], tt, __ATOMIC_RELAXED, __HIP_MEMORY_SCOPE_AGENT);
            __hip_atomic_store(&wsU[128 + gw], MAGIC, __ATOMIC_RELEASE, __HIP_MEMORY_SCOPE_AGENT);
        }
        return;
    }

    // ---------------- chain workgroup ----------------
    const int LVt[NCH] = {4, 11, 16, 16, 16};
    const int STt[NCH] = {0, 4, 15, 31, 47};
    const int myLv = LVt[wgid];
    const int mySt = STt[wgid];

    const int kc = l >> 4;
    const int bb = 16 * wv + (l & 15);            // this thread's output node

    // --- preload: convert my levels' w -> packed bf16 exp(-w) in LDS ---
    // LDS word (level lvl): f = h*1024 + t*4 + q packs pairs (k, k+1),
    // k = 16*kc(t) + 2*(4h+q), b = bb(t); chain thread t reads its 2 quads at
    // bytes lvl*8192 + t*16 and +4096 (the R8-proven fragment layout).
    const float4* w4 = (const float4*)(w + 64 + mySt * 4096);
    #pragma unroll 1
    for (int lvl = 0; lvl < myLv; ++lvl) {
        #pragma unroll
        for (int j = 0; j < 2; ++j) {
            const int pq = tid + 256 * j;
            const int pa = pq >> 4, bq = pq & 15;   // pair index, b-quad
            const int a0 = 2 * pa;
            const float4 wa = w4[lvl * 1024 + a0 * 16 + bq];
            const float4 wb = w4[lvl * 1024 + (a0 + 1) * 16 + bq];
            const int kcp = pa >> 3, j2 = pa & 7, h = j2 >> 2, q = j2 & 3;
            #pragma unroll
            for (int i = 0; i < 4; ++i) {
                const float x0 = __expf(-((const float*)&wa)[i]);
                const float x1 = __expf(-((const float*)&wb)[i]);
                uint32_t u0 = __float_as_uint(x0); u0 = (u0 + 0x7fffu + ((u0 >> 16) & 1u)) >> 16;
                uint32_t u1 = __float_as_uint(x1); u1 = (u1 + 0x7fffu + ((u1 >> 16) & 1u)) >> 16;
                const int b = 4 * bq + i;
                const int t = ((b >> 4) << 6) + (kcp << 4) + (b & 15);
                wlds[lvl * 2048 + (h << 10) + (t << 2) + q] = u0 | (u1 << 16);
            }
        }
    }

    // --- receive z (absolute) ---
    float zr, S;
    float wsink = 0.f;
    if (wgid == NCH - 1) wsink = w[SINK_BASE + bb];
    if (wgid == 0) {
        zr = -w[bb];
        S = 0.f;
    } else {
        if (tid == 0) {
            while (__hip_atomic_load(&wsU[256 + wgid - 1], __ATOMIC_ACQUIRE,
                                     __HIP_MEMORY_SCOPE_AGENT) != MAGIC)
                __builtin_amdgcn_s_sleep(2);
        }
        __syncthreads();
        zr = __hip_atomic_load(&wsF[260 + (wgid - 1) * 64 + bb], __ATOMIC_RELAXED,
                               __HIP_MEMORY_SCOPE_AGENT);
        S  = __hip_atomic_load(&wsF[260 + (wgid - 1) * 64], __ATOMIC_RELAXED,
                               __HIP_MEMORY_SCOPE_AGENT);
        __syncthreads();
        if (tid == 0)
            __hip_atomic_store(&wsU[256 + wgid - 1], 0u, __ATOMIC_RELAXED,
                               __HIP_MEMORY_SCOPE_AGENT);
    }
    if (l < 16) ubuf[0][bb] = __expf(zr - S);     // u = exp(z - S)
    if (tid == 0) zls[0] = zr;                    // z[0] (tid0 has bb==0)
    __syncthreads();

    // --- chain bodies, pure LDS (R8-proven numerics) ---
    #pragma unroll 1
    for (int lvl = 0; lvl < myLv; ++lvl) {
        const int CB = lvl & 1;
        const float s0n = zls[CB];                // next shift = z_cur[0]
        const f32x4* uq = (const f32x4*)ubuf[CB];
        const u32x4 qa = *(const u32x4*)&wlds[lvl * 2048 + tid * 4];
        const u32x4 qb = *(const u32x4*)&wlds[lvl * 2048 + 1024 + tid * 4];
        v2f acc = {0.f, 0.f};
        #pragma unroll
        for (int m = 0; m < 4; ++m) {
            const f32x4 uu = uq[4 * kc + m];
            #pragma unroll
            for (int pp = 0; pp < 2; ++pp) {
                const int j2 = 2 * m + pp;
                const unsigned int wd = (j2 < 4) ? qa[j2] : qb[j2 - 4];
                v2f wp, up;
                wp[0] = __uint_as_float(wd << 16);
                wp[1] = __uint_as_float(wd & 0xffff0000u);
                up[0] = uu[2 * pp]; up[1] = uu[2 * pp + 1];
                acc = __builtin_elementwise_fma(wp, up, acc);
            }
        }
        float p = acc[0] + acc[1];
        p += __shfl_xor(p, 16, 64);
        p += __shfl_xor(p, 32, 64);
        zr = __logf(p) + S;                       // absolute z_next[bb]
        const float un = __expf(zr - s0n);
        if (l < 16) ubuf[CB ^ 1][bb] = un;
        if (tid == 0) zls[CB ^ 1] = zr;
        S = s0n;
        __syncthreads();
    }

    if (wgid < NCH - 1) {
        // --- handoff to next wg ---
        if (l < 16)
            __hip_atomic_store(&wsF[260 + wgid * 64 + bb], zr, __ATOMIC_RELAXED,
                               __HIP_MEMORY_SCOPE_AGENT);
        asm volatile("s_waitcnt vmcnt(0)" ::: "memory");  // my store globally visible
        __syncthreads();                                   // all threads' stores done
        if (tid == 0)
            __hip_atomic_store(&wsU[256 + wgid], MAGIC, __ATOMIC_RELEASE,
                               __HIP_MEMORY_SCOPE_AGENT);
    } else {
        // --- sink fold + gold gather + output ---
        const float mm = zr - wsink;
        if (l < 16) slds[bb] = mm;
        __syncthreads();
        float vsink = 0.f;
        if (wv == 0) {
            float m = slds[l];
            float ss = 1.0f;
            #pragma unroll
            for (int d = 1; d < 64; d <<= 1) {
                const float om = __shfl_xor(m, d, 64);
                const float os = __shfl_xor(ss, d, 64);
                const float nm = fmaxf(m, om);
                ss = __expf(m - nm) * ss + __expf(om - nm) * os;
                m = nm;
            }
            vsink = m + __logf(ss);
        }
        float gval = 0.f;
        if (tid < NGOLD) {   // waves 0,1 each own one gold partial
            while (__hip_atomic_load(&wsU[128 + tid], __ATOMIC_ACQUIRE,
                                     __HIP_MEMORY_SCOPE_AGENT) != MAGIC)
                __builtin_amdgcn_s_sleep(2);
            gval = __hip_atomic_load(&wsF[tid], __ATOMIC_RELAXED,
                                     __HIP_MEMORY_SCOPE_AGENT);
            __hip_atomic_store(&wsU[128 + tid], 0u, __ATOMIC_RELAXED,
                               __HIP_MEMORY_SCOPE_AGENT);
        }
        #pragma unroll
        for (int d = 1; d < 64; d <<= 1) gval += __shfl_xor(gval, d, 64);
        if (l == 0) gred[wv] = gval;    // waves 2,3 write 0
        __syncthreads();
        if (tid == 0)
            out[0] = gred[0] + gred[1] + gred[2] + gred[3] + vsink;
    }
}

extern "C" void kernel_launch(void* const* d_in, const int* in_sizes, int n_in,
                              void* d_out, int out_size, void* d_ws, size_t ws_size,
                              hipStream_t stream) {
    const int*   g = (const int*)d_in[0];
    const float* w = (const float*)d_in[1];
    float* out     = (float*)d_out;
    float* ws      = (float*)d_ws;
    const int E = in_sizes[0] / 3;   // 258176

    fused_kernel<<<NCH + NGOLD, TPB, 0, stream>>>(g, w, ws, out, E);
}

// Round 11
// 35.021 us; speedup vs baseline: 1.0414x; 1.0414x over previous
//
#include <hip/hip_runtime.h>
#include <hip/hip_bf16.h>
#include <cstdint>

// GraphLoss: layered lattice DAG (64 layers x 64 nodes, dense bipartite).
// result = sum(w*gold) + logsumexp over all source->sink paths of (-path weight).
//
// R11: barrier-cadenced producer/consumer, no flags, no counted-vmcnt handshakes.
//  * consumers: 4 waves, R8-proven body; multiplicative recursion
//      u_next[b] = (sum_a u[a]*exp(-W[a][b])) * rcp(rho),  rho = prev u[0] (LDS)
//      LS += log(rho) off-path. No log/exp on the level critical chain.
//      Consumer waves have NO asm loads / NO vmcnt (per-wave counters!).
//  * producer: 1 wave, global_load_lds only (LDS targets -> no register
//      hazard), 8-slot ring + dummy slot 8 for uniform tail (no peel),
//      sched_barrier(0) around a uniform vmcnt(40), s_barrier cadence
//      guarantees level t landed before consumers read it.
//
// Edge layout: e in [0,64): source->layer1 ; e = 64 + L*4096 + a*64 + b ;
// e = 258112 + j: layer64 node j -> sink.

typedef float v2f   __attribute__((ext_vector_type(2)));
typedef float f32x4 __attribute__((ext_vector_type(4)));
typedef unsigned int u32x4 __attribute__((ext_vector_type(4)));
typedef __attribute__((address_space(3))) unsigned int as3_u32;
typedef __attribute__((address_space(1))) const unsigned int as1_u32;

#define NLV 63
#define NPACK (63 * 2048)            // 8KB/level packed bf16 pairs
#define SINK_BASE (64 + 63 * 4096)   // 258112
#define NPB 256

// ---------------------------------------------------------------------------
// prep (R8 verbatim, proven absmax 0.0): word f = L*2048 + h*1024 + t*4 + q,
// t in [0,256): kc=(t&63)>>4, bb=16*(t>>6)+(t&15), pair k = 16kc+2*(4h+q):
// packs bf16(exp(-w[e0])) | bf16(exp(-w[e0+64]))<<16, e0 = 64+L*4096+k*64+bb.
// Consumer thread t reads words [4t,4t+4) and [1024+4t,...). Coalesced.
// Plus 256 block partials of sum(w*gold).
__global__ __launch_bounds__(512)
void prep_kernel(const int* __restrict__ g, const float* __restrict__ w,
                 unsigned int* __restrict__ wpk, float* __restrict__ partial, int E) {
    const int f = blockIdx.x * blockDim.x + threadIdx.x;
    if (f < NPACK) {
        const int L = f >> 11;
        const int r = f & 2047;
        const int h = (r >> 10) & 1;
        const int t = (r >> 2) & 255;
        const int q = r & 3;
        const int wvp = t >> 6, ls = t & 63;
        const int kcp = ls >> 4, bp = 16 * wvp + (ls & 15);
        const int k = 16 * kcp + 2 * (4 * h + q);
        const int e0 = 64 + L * 4096 + k * 64 + bp;
        const float x0 = __expf(-w[e0]);
        const float x1 = __expf(-w[e0 + 64]);
        uint32_t u0 = __float_as_uint(x0); u0 = (u0 + 0x7fffu + ((u0 >> 16) & 1u)) >> 16;
        uint32_t u1 = __float_as_uint(x1); u1 = (u1 + 0x7fffu + ((u1 >> 16) & 1u)) >> 16;
        wpk[f] = u0 | (u1 << 16);
    }
    const bool is64 = (g[1] == 0);
    float s = 0.f;
    const int stride = gridDim.x * blockDim.x;
    for (int e = f; e < E; e += stride) {
        const int idx = 3 * e + 2;
        const int gv = is64 ? g[2 * idx] : g[idx];
        s += w[e] * (float)gv;
    }
    #pragma unroll
    for (int dd = 1; dd < 64; dd <<= 1) s += __shfl_xor(s, dd, 64);
    __shared__ float lsm[8];
    const int wv = threadIdx.x >> 6, ln = threadIdx.x & 63;
    if (ln == 0) lsm[wv] = s;
    __syncthreads();
    if (threadIdx.x == 0) {
        float tt = 0.f;
        #pragma unroll
        for (int i = 0; i < 8; ++i) tt += lsm[i];
        partial[blockIdx.x] = tt;
    }
}

// ---------------------------------------------------------------------------
// seq: 320 threads. waves 0-3 = consumers; wave 4 = producer (DMA ring).
__global__ __launch_bounds__(320, 1)
void seq_kernel(const float* __restrict__ w, const unsigned int* __restrict__ wpk,
                const float* __restrict__ partial, float* __restrict__ out) {
    __shared__ __align__(16) unsigned int wring[9 * 2048];   // 8 slots + dummy
    __shared__ __align__(16) float ubuf[2][64];
    __shared__ float P[2];                                    // rho dbuf
    __shared__ float slds[64];

    const int tid = threadIdx.x;
    const int wv = tid >> 6, l = tid & 63;
    const int kc = l >> 4;
    const int bb = 16 * wv + (l & 15);

    float LS = 0.f, uf = 0.f, wsink = 0.f, gs = 0.f;

#define BAR() do {                                                             \
    asm volatile("s_waitcnt lgkmcnt(0)" ::: "memory");                         \
    __builtin_amdgcn_s_barrier();                                              \
} while (0)

#define PISSUE(LVL, SLOT) do {                                                 \
    const unsigned int* gsrc = wpk + (LVL) * 2048 + (l << 2);                  \
    unsigned int* ldst = &wring[(SLOT) * 2048];                                \
    _Pragma("unroll")                                                          \
    for (int q = 0; q < 8; ++q)                                                \
        __builtin_amdgcn_global_load_lds((as1_u32*)(gsrc + (q << 8)),          \
                                         (as3_u32*)(ldst + (q << 8)), 16, 0, 0);\
} while (0)

    if (tid < 256) {
        // consumer init: u_1[b] = exp(z1[b]-z1[0]), z1 = -w[b]
        const float z10 = -w[0];
        LS = z10;
        uf = __expf(-w[bb] - z10);
        wsink = w[SINK_BASE + bb];
        #pragma unroll
        for (int i = 0; i < 4; ++i) gs += partial[l + (i << 6)];
        if (l < 16) ubuf[0][bb] = uf;
        if (tid == 0) { P[0] = 1.0f; }
    } else {
        // producer prologue: levels 0..5 -> slots 0..5; leave {1..5}=40 in flight
        #pragma unroll 1
        for (int lvl = 0; lvl < 6; ++lvl) PISSUE(lvl, lvl);
        __builtin_amdgcn_sched_barrier(0);
        asm volatile("s_waitcnt vmcnt(40)" ::: "memory");   // level 0 landed
        __builtin_amdgcn_sched_barrier(0);
    }
    BAR();

    #pragma unroll 1
    for (int t = 0; t < NLV; ++t) {
        if (tid >= 256) {
            // issue level t+6 (or a dummy re-read of 62 into slot 8: keeps
            // vmcnt arithmetic uniform with NO register hazard - LDS target)
            const int lvl  = (t <= 56) ? (t + 6) : 62;
            const int slot = (t <= 56) ? ((t + 6) & 7) : 8;
            PISSUE(lvl, slot);
            __builtin_amdgcn_sched_barrier(0);
            asm volatile("s_waitcnt vmcnt(40)" ::: "memory");  // level t+1 landed
            __builtin_amdgcn_sched_barrier(0);
        } else {
            const float rho = P[t & 1];
            float c;
            asm("v_rcp_f32 %0, %1" : "=v"(c) : "v"(rho));      // ready before fold
            const unsigned int* wslot = &wring[(t & 7) * 2048];
            const u32x4 qa = *(const u32x4*)&wslot[tid << 2];
            const u32x4 qb = *(const u32x4*)&wslot[1024 + (tid << 2)];
            const f32x4* uq = (const f32x4*)ubuf[t & 1];
            v2f acc = {0.f, 0.f};
            #pragma unroll
            for (int m = 0; m < 4; ++m) {
                const f32x4 uu = uq[4 * kc + m];
                #pragma unroll
                for (int pp = 0; pp < 2; ++pp) {
                    const int j2 = 2 * m + pp;
                    const unsigned int wd = (j2 < 4) ? qa[j2] : qb[j2 - 4];
                    v2f wp, up;
                    wp[0] = __uint_as_float(wd << 16);
                    wp[1] = __uint_as_float(wd & 0xffff0000u);
                    up[0] = uu[2 * pp]; up[1] = uu[2 * pp + 1];
                    acc = __builtin_elementwise_fma(wp, up, acc);
                }
            }
            float p = acc[0] + acc[1];
            p += __shfl_xor(p, 16, 64);
            p += __shfl_xor(p, 32, 64);    // full 64-term sum for bb
            uf = p * c;                    // u_next, scale resets every level
            LS += __logf(rho);             // off critical path
            if (l < 16) ubuf[(t + 1) & 1][bb] = uf;
            if (tid == 0) P[(t + 1) & 1] = uf;   // rho_next = u_next[0]
        }
        BAR();
    }

    if (tid >= 256) {
        asm volatile("s_waitcnt vmcnt(0)" ::: "memory");  // drain dummies
    } else {
        const float m0 = LS + __logf(uf) - wsink;         // z_64[bb] - wsink
        if (l < 16) slds[bb] = m0;
    }
    BAR();

    if (tid < 64) {
        float m = slds[tid];
        float s = 1.0f;
        #pragma unroll
        for (int d = 1; d < 64; d <<= 1) {
            const float om = __shfl_xor(m, d, 64);
            const float os = __shfl_xor(s, d, 64);
            const float nm = fmaxf(m, om);
            s = __expf(m - nm) * s + __expf(om - nm) * os;
            m = nm;
        }
        const float vsink = m + __logf(s);
        #pragma unroll
        for (int d = 1; d < 64; d <<= 1) gs += __shfl_xor(gs, d, 64);
        if (tid == 0) out[0] = gs + vsink;
    }
}

extern "C" void kernel_launch(void* const* d_in, const int* in_sizes, int n_in,
                              void* d_out, int out_size, void* d_ws, size_t ws_size,
                              hipStream_t stream) {
    const int*   g = (const int*)d_in[0];
    const float* w = (const float*)d_in[1];
    float* out     = (float*)d_out;
    unsigned int* wpk = (unsigned int*)d_ws;        // 129024 u32
    float* partial = (float*)(wpk + NPACK);         // 256 floats
    const int E = in_sizes[0] / 3;                  // 258176

    prep_kernel<<<NPB, 512, 0, stream>>>(g, w, wpk, partial, E);
    seq_kernel<<<1, 320, 0, stream>>>(w, wpk, partial, out);
}